// Round 8
// baseline (156.089 us; speedup 1.0000x reference)
//
#include <hip/hip_runtime.h>
#include <math.h>

#define OUT 260
#define TAPS 6
#define IMG_H 2048
#define IMG_W 2048
#define ROW_F (IMG_W * 3)            // 6144 floats per image row
#define NB 10
#define TH 0.8f
#define SEGS 6                       // 5 segs * 48 + 1 seg * 20
#define QB 48
#define G 4                          // output rows per block
#define LROW 1152                    // floats per combined LDS row (worst span 47*7.88+6 px -> 1131 fl)
#define MAXM 32                      // max rows in 4-p union (3*8+6=30)
#define NF 5                         // static f-groups: NF*256 >= LROW

__device__ __forceinline__ float sincf(float x) {
    if (x == 0.0f) return 1.0f;
    float px = 3.14159265358979323846f * x;
    return __sinf(px) / px;
}

// Record layout per (box, idx), 16 dwords = 64 B:
//   f[0..5]  : normalized weights (vertical table: also * vmask)
//   i[8..13] : horizontal: clamped absolute float index (x0+t)*3
//              vertical:   clamped absolute row index (t+y0)
//   i[14]    : vertical: unclamped tap base (floor(src)-2); horizontal: 0

__global__ __launch_bounds__(320) void tables_kernel(
    const float* __restrict__ scores, const float* __restrict__ boxes,
    float* __restrict__ htab, float* __restrict__ vtab)
{
    const int box = blockIdx.x;
    const float b0 = boxes[box * 4 + 0];
    const float b1 = boxes[box * 4 + 1];
    const float b2 = boxes[box * 4 + 2];
    const float b3 = boxes[box * 4 + 3];

    const int y0 = (int)(b0 * (float)IMG_H);
    const int x0 = (int)(b1 * (float)IMG_W);
    const int y1 = (int)(b2 * (float)IMG_H);
    const int x1 = (int)(b3 * (float)IMG_W);
    const int ch = max(y1 - y0, 1);
    const int cw = max(x1 - x0, 1);

    const bool valid = (scores[0] >= TH) && (scores[box] >= TH)
                    && (b1 >= 0.0f) && (b3 <= 1.0f);
    const float vmask = valid ? 1.0f : 0.0f;

    const int t = threadIdx.x;
    if (t >= OUT) return;

    // ---- horizontal record ----
    {
        const float src = ((float)t + 0.5f) * ((float)cw / (float)OUT) - 0.5f;
        const int base = (int)floorf(src) - 2;
        float w[TAPS]; int id[TAPS];
        float s = 0.0f;
        #pragma unroll
        for (int k = 0; k < TAPS; ++k) {
            const float d = src - (float)(base + k);
            const float wv = (fabsf(d) < 3.0f) ? sincf(d) * sincf(d * (1.0f / 3.0f)) : 0.0f;
            w[k] = wv; s += wv;
            int tt = base + k; tt = tt < 0 ? 0 : tt; tt = tt > cw - 1 ? cw - 1 : tt;
            id[k] = (x0 + tt) * 3;
        }
        const float inv = 1.0f / s;
        float* h = htab + ((size_t)(box * OUT + t) << 4);
        int*   hi = (int*)h;
        #pragma unroll
        for (int k = 0; k < TAPS; ++k) { h[k] = w[k] * inv; hi[8 + k] = id[k]; }
        h[6] = 0.0f; h[7] = 0.0f; hi[14] = 0; hi[15] = 0;
    }

    // ---- vertical record (vmask folded in; unclamped base stored) ----
    {
        const float src = ((float)t + 0.5f) * ((float)ch / (float)OUT) - 0.5f;
        const int base = (int)floorf(src) - 2;
        float w[TAPS]; int id[TAPS];
        float s = 0.0f;
        #pragma unroll
        for (int k = 0; k < TAPS; ++k) {
            const float d = src - (float)(base + k);
            const float wv = (fabsf(d) < 3.0f) ? sincf(d) * sincf(d * (1.0f / 3.0f)) : 0.0f;
            w[k] = wv; s += wv;
            int tt = base + k; tt = tt < 0 ? 0 : tt; tt = tt > ch - 1 ? ch - 1 : tt;
            id[k] = tt + y0;
        }
        const float inv = vmask / s;
        float* v = vtab + ((size_t)(box * OUT + t) << 4);
        int*   vi = (int*)v;
        #pragma unroll
        for (int k = 0; k < TAPS; ++k) { v[k] = w[k] * inv; vi[8 + k] = id[k]; }
        v[6] = 0.0f; v[7] = 0.0f; vi[14] = base; vi[15] = 0;
    }
}

// Block = (box, 4-row p-group, 48-col segment). Stage the union of the 4
// vertical 6-tap windows ONCE (m = delta + 6 rows, <= 30), combining into 4
// LDS rows using LDS-resident weight tables (no per-thread dynamic arrays).
__global__ __launch_bounds__(64) void crop_resize_pg(
    const float* __restrict__ img,
    const float* __restrict__ boxes,
    const float* __restrict__ htab,
    const float* __restrict__ vtab,
    float* __restrict__ out)
{
    const int seg = blockIdx.x;      // 0..5
    const int pg  = blockIdx.y;      // 0..64
    const int box = blockIdx.z;      // 0..9
    const int q0  = seg * QB;
    const int qcount = min(QB, OUT - q0);   // 48 or 20
    const int p0 = pg * G;
    const int tid = threadIdx.x;

    __shared__ float ldsrow[G * LROW];
    __shared__ float wlds[G * MAXM];
    __shared__ int   rowlds[MAXM];

    // box vertical geometry
    const float b0 = boxes[box * 4 + 0];
    const float b2 = boxes[box * 4 + 2];
    const int y0 = (int)(b0 * (float)IMG_H);
    const int y1 = (int)(b2 * (float)IMG_H);
    const int ch = max(y1 - y0, 1);

    // union bounds from unclamped bases
    const int base0 = ((const int*)(vtab + ((size_t)(box * OUT + p0) << 4)))[14];
    const int baseL = ((const int*)(vtab + ((size_t)(box * OUT + p0 + G - 1) << 4)))[14];
    int m = baseL - base0 + TAPS;
    m = m < TAPS ? TAPS : (m > MAXM ? MAXM : m);

    // fill weight table: wlds[g][j] = weight of union row j for output p0+g
    for (int idx = tid; idx < G * MAXM; idx += 64) {
        const int g = idx >> 5;          // /MAXM
        const int j = idx & (MAXM - 1);
        const float* vg = vtab + ((size_t)(box * OUT + p0 + g) << 4);
        const int dg = ((const int*)vg)[14] - base0;
        const int k = j - dg;
        wlds[idx] = (k >= 0 && k < TAPS) ? vg[k] : 0.0f;
    }
    // fill row table: clamped absolute rows
    if (tid < MAXM) {
        int r = base0 + tid;
        r = r < 0 ? 0 : (r > ch - 1 ? ch - 1 : r);
        rowlds[tid] = r + y0;
    }

    // per-thread horizontal record prefetch (before barrier)
    const int q = q0 + tid;
    const bool qact = (tid < qcount);
    float hw0 = 0, hw1 = 0, hw2 = 0, hw3 = 0, hw4 = 0, hw5 = 0;
    int li0 = 0, li1 = 0, li2 = 0, li3 = 0, li4 = 0, li5 = 0;
    if (qact) {
        const float* h = htab + ((size_t)(box * OUT + q) << 4);
        const int*  hi = (const int*)h;
        const float4 w01 = *(const float4*)(h);
        const float4 w23 = *(const float4*)(h + 4);
        hw0 = w01.x; hw1 = w01.y; hw2 = w01.z; hw3 = w01.w;
        hw4 = w23.x; hw5 = w23.y;
        li0 = hi[8]; li1 = hi[9]; li2 = hi[10];
        li3 = hi[11]; li4 = hi[12]; li5 = hi[13];
    }

    // staged span
    const int* hi_first = (const int*)(htab + ((size_t)(box * OUT + q0) << 4));
    const int* hi_last  = (const int*)(htab + ((size_t)(box * OUT + q0 + qcount - 1) << 4));
    const int start_f = hi_first[8] & ~3;
    const int n_f     = ((hi_last[13] + 3) - start_f + 3) & ~3;   // <= LROW

    __syncthreads();   // single wave: cheap; makes wlds/rowlds visible

    // ---- stage: loop union rows (dynamic), static NF f-groups x G accumulators ----
    float4 acc[NF][G];
    #pragma unroll
    for (int i = 0; i < NF; ++i)
        #pragma unroll
        for (int g = 0; g < G; ++g)
            acc[i][g] = make_float4(0.f, 0.f, 0.f, 0.f);

    for (int j = 0; j < m; ++j) {
        const int row = rowlds[j];
        const float w0 = wlds[0 * MAXM + j];
        const float w1 = wlds[1 * MAXM + j];
        const float w2 = wlds[2 * MAXM + j];
        const float w3 = wlds[3 * MAXM + j];
        const float* rp = img + (size_t)row * ROW_F + start_f;
        #pragma unroll
        for (int i = 0; i < NF; ++i) {
            const int f = tid * 4 + i * 256;
            if (f < n_f) {
                const float4 v = *(const float4*)(rp + f);
                acc[i][0].x = fmaf(w0, v.x, acc[i][0].x); acc[i][0].y = fmaf(w0, v.y, acc[i][0].y);
                acc[i][0].z = fmaf(w0, v.z, acc[i][0].z); acc[i][0].w = fmaf(w0, v.w, acc[i][0].w);
                acc[i][1].x = fmaf(w1, v.x, acc[i][1].x); acc[i][1].y = fmaf(w1, v.y, acc[i][1].y);
                acc[i][1].z = fmaf(w1, v.z, acc[i][1].z); acc[i][1].w = fmaf(w1, v.w, acc[i][1].w);
                acc[i][2].x = fmaf(w2, v.x, acc[i][2].x); acc[i][2].y = fmaf(w2, v.y, acc[i][2].y);
                acc[i][2].z = fmaf(w2, v.z, acc[i][2].z); acc[i][2].w = fmaf(w2, v.w, acc[i][2].w);
                acc[i][3].x = fmaf(w3, v.x, acc[i][3].x); acc[i][3].y = fmaf(w3, v.y, acc[i][3].y);
                acc[i][3].z = fmaf(w3, v.z, acc[i][3].z); acc[i][3].w = fmaf(w3, v.w, acc[i][3].w);
            }
        }
    }
    #pragma unroll
    for (int i = 0; i < NF; ++i) {
        const int f = tid * 4 + i * 256;
        if (f < n_f) {
            #pragma unroll
            for (int g = 0; g < G; ++g)
                *(float4*)(ldsrow + g * LROW + f) = acc[i][g];
        }
    }
    __syncthreads();

    // ---- compute: each active lane emits 4 output rows at its q ----
    if (qact) {
        const int i0 = li0 - start_f, i1 = li1 - start_f, i2 = li2 - start_f;
        const int i3 = li3 - start_f, i4 = li4 - start_f, i5 = li5 - start_f;
        #pragma unroll
        for (int g = 0; g < G; ++g) {
            const float* l = ldsrow + g * LROW;
            float a0, a1, a2;
            a0 = hw0 * l[i0 + 0]; a1 = hw0 * l[i0 + 1]; a2 = hw0 * l[i0 + 2];
            a0 = fmaf(hw1, l[i1 + 0], a0); a1 = fmaf(hw1, l[i1 + 1], a1); a2 = fmaf(hw1, l[i1 + 2], a2);
            a0 = fmaf(hw2, l[i2 + 0], a0); a1 = fmaf(hw2, l[i2 + 1], a1); a2 = fmaf(hw2, l[i2 + 2], a2);
            a0 = fmaf(hw3, l[i3 + 0], a0); a1 = fmaf(hw3, l[i3 + 1], a1); a2 = fmaf(hw3, l[i3 + 2], a2);
            a0 = fmaf(hw4, l[i4 + 0], a0); a1 = fmaf(hw4, l[i4 + 1], a1); a2 = fmaf(hw4, l[i4 + 2], a2);
            a0 = fmaf(hw5, l[i5 + 0], a0); a1 = fmaf(hw5, l[i5 + 1], a1); a2 = fmaf(hw5, l[i5 + 2], a2);
            const size_t o = (((size_t)box * OUT + (p0 + g)) * OUT + q) * 3;
            out[o + 0] = a0;
            out[o + 1] = a1;
            out[o + 2] = a2;
        }
    }
}

// ---------------- Fallback (round-4 single kernel, no workspace) ----------------
__global__ __launch_bounds__(256) void crop_resize_fallback(
    const float* __restrict__ scores, const float* __restrict__ boxes,
    const float* __restrict__ img, float* __restrict__ out)
{
    const int p = blockIdx.x, box = blockIdx.y;
    const float b0 = boxes[box*4+0], b1 = boxes[box*4+1];
    const float b2 = boxes[box*4+2], b3 = boxes[box*4+3];
    const int y0 = (int)(b0*(float)IMG_H), x0 = (int)(b1*(float)IMG_W);
    const int y1 = (int)(b2*(float)IMG_H), x1 = (int)(b3*(float)IMG_W);
    const int ch = max(y1-y0,1), cw = max(x1-x0,1);
    const bool valid = (scores[0]>=TH)&&(scores[box]>=TH)&&(b1>=0.0f)&&(b3<=1.0f);
    const float vmask = valid?1.0f:0.0f;
    float wh[TAPS]; int ih[TAPS];
    {
        const float src = ((float)p+0.5f)*((float)ch/(float)OUT)-0.5f;
        const int base = (int)floorf(src)-2;
        float s = 0.0f;
        #pragma unroll
        for (int a = 0; a < TAPS; ++a) {
            const float d = src-(float)(base+a);
            const float w = (fabsf(d)<3.0f)?sincf(d)*sincf(d*(1.0f/3.0f)):0.0f;
            wh[a]=w; s+=w;
            int t=base+a; t=t<0?0:t; t=t>ch-1?ch-1:t; ih[a]=t+y0;
        }
        const float inv = 1.0f/s;
        #pragma unroll
        for (int a = 0; a < TAPS; ++a) wh[a]*=inv;
    }
    const int start_f = (x0*3)&~3;
    const int end_f = (x0+cw)*3;
    const int n_f = end_f-start_f;
    __shared__ float lds[6152];
    {
        const float* r0 = img+(size_t)ih[0]*ROW_F+start_f;
        const float* r1 = img+(size_t)ih[1]*ROW_F+start_f;
        const float* r2 = img+(size_t)ih[2]*ROW_F+start_f;
        const float* r3 = img+(size_t)ih[3]*ROW_F+start_f;
        const float* r4 = img+(size_t)ih[4]*ROW_F+start_f;
        const float* r5 = img+(size_t)ih[5]*ROW_F+start_f;
        for (int f = threadIdx.x*4; f < n_f; f += 256*4) {
            const float4 u0=*(const float4*)(r0+f), u1=*(const float4*)(r1+f);
            const float4 u2=*(const float4*)(r2+f), u3=*(const float4*)(r3+f);
            const float4 u4=*(const float4*)(r4+f), u5=*(const float4*)(r5+f);
            float4 acc;
            acc.x=wh[0]*u0.x+wh[1]*u1.x+wh[2]*u2.x+wh[3]*u3.x+wh[4]*u4.x+wh[5]*u5.x;
            acc.y=wh[0]*u0.y+wh[1]*u1.y+wh[2]*u2.y+wh[3]*u3.y+wh[4]*u4.y+wh[5]*u5.y;
            acc.z=wh[0]*u0.z+wh[1]*u1.z+wh[2]*u2.z+wh[3]*u3.z+wh[4]*u4.z+wh[5]*u5.z;
            acc.w=wh[0]*u0.w+wh[1]*u1.w+wh[2]*u2.w+wh[3]*u3.w+wh[4]*u4.w+wh[5]*u5.w;
            *(float4*)(lds+f)=acc;
        }
    }
    __syncthreads();
    const float wscale = (float)cw/(float)OUT;
    for (int q = threadIdx.x; q < OUT; q += 256) {
        const float src = ((float)q+0.5f)*wscale-0.5f;
        const int basew = (int)floorf(src)-2;
        float ww[TAPS]; float s = 0.0f;
        #pragma unroll
        for (int k = 0; k < TAPS; ++k) {
            const float d = src-(float)(basew+k);
            const float w = (fabsf(d)<3.0f)?sincf(d)*sincf(d*(1.0f/3.0f)):0.0f;
            ww[k]=w; s+=w;
        }
        const float inv = 1.0f/s;
        float a0=0,a1=0,a2=0;
        #pragma unroll
        for (int k = 0; k < TAPS; ++k) {
            int t=basew+k; t=t<0?0:t; t=t>cw-1?cw-1:t;
            const int hb=(x0+t)*3-start_f;
            a0=fmaf(ww[k],lds[hb+0],a0);
            a1=fmaf(ww[k],lds[hb+1],a1);
            a2=fmaf(ww[k],lds[hb+2],a2);
        }
        const float mfac = vmask*inv;
        const size_t o = (((size_t)box*OUT+p)*OUT+q)*3;
        out[o+0]=a0*mfac; out[o+1]=a1*mfac; out[o+2]=a2*mfac;
    }
}

extern "C" void kernel_launch(void* const* d_in, const int* in_sizes, int n_in,
                              void* d_out, int out_size, void* d_ws, size_t ws_size,
                              hipStream_t stream) {
    const float* scores = (const float*)d_in[0];   // (100,)
    const float* boxes  = (const float*)d_in[1];   // (100,4)
    const float* img    = (const float*)d_in[2];   // (1,2048,2048,3)
    float* out = (float*)d_out;                    // (10,260,260,3)

    const size_t tab_bytes = (size_t)NB * OUT * 16 * sizeof(float);  // 166,400 B each
    if (ws_size < 2 * tab_bytes) {
        crop_resize_fallback<<<dim3(OUT, NB), dim3(256), 0, stream>>>(scores, boxes, img, out);
        return;
    }
    float* htab = (float*)d_ws;
    float* vtab = (float*)((char*)d_ws + tab_bytes);

    tables_kernel<<<dim3(NB), dim3(320), 0, stream>>>(scores, boxes, htab, vtab);
    crop_resize_pg<<<dim3(SEGS, OUT / G, NB), dim3(64), 0, stream>>>(img, boxes, htab, vtab, out);
}

// Round 9
// 116.543 us; speedup vs baseline: 1.3393x; 1.3393x over previous
//
#include <hip/hip_runtime.h>
#include <math.h>

#define OUT 260
#define TAPS 6
#define IMG_H 2048
#define IMG_W 2048
#define ROW_F (IMG_W * 3)            // 6144 floats per image row
#define NB 10
#define TH 0.8f
#define SEGS 6                       // 5 segs * 48 + 1 seg * 20
#define QB 48
#define G 4                          // output rows per block
#define LROW 1152                    // floats per combined LDS row (worst span ~1140)
#define MAXM 32                      // max rows in 4-p union (3*ceil(7.88)+6=30)

__device__ __forceinline__ float sincf(float x) {
    if (x == 0.0f) return 1.0f;
    float px = 3.14159265358979323846f * x;
    return __sinf(px) / px;
}

// Record layout per (box, idx), 16 dwords = 64 B:
//   f[0..5]  : normalized weights (vertical table: also * vmask)
//   i[8..13] : horizontal: clamped absolute float index (x0+t)*3
//              vertical:   clamped absolute row index (t+y0)
//   i[14]    : vertical: unclamped tap base (floor(src)-2); horizontal: 0

__global__ __launch_bounds__(320) void tables_kernel(
    const float* __restrict__ scores, const float* __restrict__ boxes,
    float* __restrict__ htab, float* __restrict__ vtab)
{
    const int box = blockIdx.x;
    const float b0 = boxes[box * 4 + 0];
    const float b1 = boxes[box * 4 + 1];
    const float b2 = boxes[box * 4 + 2];
    const float b3 = boxes[box * 4 + 3];

    const int y0 = (int)(b0 * (float)IMG_H);
    const int x0 = (int)(b1 * (float)IMG_W);
    const int y1 = (int)(b2 * (float)IMG_H);
    const int x1 = (int)(b3 * (float)IMG_W);
    const int ch = max(y1 - y0, 1);
    const int cw = max(x1 - x0, 1);

    const bool valid = (scores[0] >= TH) && (scores[box] >= TH)
                    && (b1 >= 0.0f) && (b3 <= 1.0f);
    const float vmask = valid ? 1.0f : 0.0f;

    const int t = threadIdx.x;
    if (t >= OUT) return;

    // ---- horizontal record ----
    {
        const float src = ((float)t + 0.5f) * ((float)cw / (float)OUT) - 0.5f;
        const int base = (int)floorf(src) - 2;
        float w[TAPS]; int id[TAPS];
        float s = 0.0f;
        #pragma unroll
        for (int k = 0; k < TAPS; ++k) {
            const float d = src - (float)(base + k);
            const float wv = (fabsf(d) < 3.0f) ? sincf(d) * sincf(d * (1.0f / 3.0f)) : 0.0f;
            w[k] = wv; s += wv;
            int tt = base + k; tt = tt < 0 ? 0 : tt; tt = tt > cw - 1 ? cw - 1 : tt;
            id[k] = (x0 + tt) * 3;
        }
        const float inv = 1.0f / s;
        float* h = htab + ((size_t)(box * OUT + t) << 4);
        int*   hi = (int*)h;
        #pragma unroll
        for (int k = 0; k < TAPS; ++k) { h[k] = w[k] * inv; hi[8 + k] = id[k]; }
        h[6] = 0.0f; h[7] = 0.0f; hi[14] = 0; hi[15] = 0;
    }

    // ---- vertical record (vmask folded in; unclamped base stored) ----
    {
        const float src = ((float)t + 0.5f) * ((float)ch / (float)OUT) - 0.5f;
        const int base = (int)floorf(src) - 2;
        float w[TAPS]; int id[TAPS];
        float s = 0.0f;
        #pragma unroll
        for (int k = 0; k < TAPS; ++k) {
            const float d = src - (float)(base + k);
            const float wv = (fabsf(d) < 3.0f) ? sincf(d) * sincf(d * (1.0f / 3.0f)) : 0.0f;
            w[k] = wv; s += wv;
            int tt = base + k; tt = tt < 0 ? 0 : tt; tt = tt > ch - 1 ? ch - 1 : tt;
            id[k] = tt + y0;
        }
        const float inv = vmask / s;
        float* v = vtab + ((size_t)(box * OUT + t) << 4);
        int*   vi = (int*)v;
        #pragma unroll
        for (int k = 0; k < TAPS; ++k) { v[k] = w[k] * inv; vi[8 + k] = id[k]; }
        v[6] = 0.0f; v[7] = 0.0f; vi[14] = base; vi[15] = 0;
    }
}

// Block = (box, 4-row p-group, 48-col segment), 256 threads (4 waves).
// Stage the union of the 4 vertical 6-tap windows ONCE (m <= 30 rows),
// combine into 4 LDS rows; wave w computes output row p0+w.
__global__ __launch_bounds__(256) void crop_resize_pg(
    const float* __restrict__ img,
    const float* __restrict__ boxes,
    const float* __restrict__ htab,
    const float* __restrict__ vtab,
    float* __restrict__ out)
{
    const int seg = blockIdx.x;      // 0..5
    const int pg  = blockIdx.y;      // 0..64
    const int box = blockIdx.z;      // 0..9
    const int q0  = seg * QB;
    const int qcount = min(QB, OUT - q0);   // 48 or 20
    const int p0 = pg * G;
    const int tid = threadIdx.x;

    __shared__ float ldsrow[G * LROW];
    __shared__ float wlds[G * MAXM];
    __shared__ int   rowlds[MAXM];

    // box vertical geometry
    const float b0 = boxes[box * 4 + 0];
    const float b2 = boxes[box * 4 + 2];
    const int y0 = (int)(b0 * (float)IMG_H);
    const int y1 = (int)(b2 * (float)IMG_H);
    const int ch = max(y1 - y0, 1);

    // union bounds from unclamped bases
    const int base0 = ((const int*)(vtab + ((size_t)(box * OUT + p0) << 4)))[14];
    const int baseL = ((const int*)(vtab + ((size_t)(box * OUT + p0 + G - 1) << 4)))[14];
    int m = baseL - base0 + TAPS;
    m = m < TAPS ? TAPS : (m > MAXM ? MAXM : m);

    // fill weight table: wlds[g*MAXM+j] = weight of union row j for output p0+g
    if (tid < G * MAXM) {
        const int g = tid >> 5;          // /MAXM
        const int j = tid & (MAXM - 1);
        const float* vg = vtab + ((size_t)(box * OUT + p0 + g) << 4);
        const int dg = ((const int*)vg)[14] - base0;
        const int k = j - dg;
        wlds[tid] = (k >= 0 && k < TAPS) ? vg[k] : 0.0f;
    }
    // fill row table: clamped absolute rows
    if (tid < MAXM) {
        int r = base0 + tid;
        r = r < 0 ? 0 : (r > ch - 1 ? ch - 1 : r);
        rowlds[tid] = r + y0;
    }

    // per-thread horizontal record prefetch (before barrier):
    // wave w (gsel) covers output row p0+w, lane qi covers column q0+qi
    const int gsel = tid >> 6;
    const int qi   = tid & 63;
    const bool qact = (qi < qcount);
    const int q = q0 + qi;
    float hw0 = 0, hw1 = 0, hw2 = 0, hw3 = 0, hw4 = 0, hw5 = 0;
    int li0 = 0, li1 = 0, li2 = 0, li3 = 0, li4 = 0, li5 = 0;
    if (qact) {
        const float* h = htab + ((size_t)(box * OUT + q) << 4);
        const int*  hi = (const int*)h;
        const float4 w01 = *(const float4*)(h);
        const float4 w23 = *(const float4*)(h + 4);
        hw0 = w01.x; hw1 = w01.y; hw2 = w01.z; hw3 = w01.w;
        hw4 = w23.x; hw5 = w23.y;
        li0 = hi[8]; li1 = hi[9]; li2 = hi[10];
        li3 = hi[11]; li4 = hi[12]; li5 = hi[13];
    }

    // staged span
    const int* hi_first = (const int*)(htab + ((size_t)(box * OUT + q0) << 4));
    const int* hi_last  = (const int*)(htab + ((size_t)(box * OUT + q0 + qcount - 1) << 4));
    const int start_f = hi_first[8] & ~3;
    const int n_f     = ((hi_last[13] + 3) - start_f + 3) & ~3;   // <= LROW

    __syncthreads();   // wlds/rowlds visible to all 4 waves

    // ---- stage: loop union rows (dynamic), 2 static f-groups x G accumulators ----
    const int f0 = tid * 4;              // group 0: floats [0, 1024)
    const int f1 = (tid + 256) * 4;      // group 1: floats [1024, 2048) -> covers LROW
    const bool a0ok = (f0 < n_f);
    const bool a1ok = (f1 < n_f);

    float4 accA[G], accB[G];
    #pragma unroll
    for (int g = 0; g < G; ++g) {
        accA[g] = make_float4(0.f, 0.f, 0.f, 0.f);
        accB[g] = make_float4(0.f, 0.f, 0.f, 0.f);
    }

    for (int j = 0; j < m; ++j) {
        const int row = rowlds[j];
        const float w0 = wlds[0 * MAXM + j];
        const float w1 = wlds[1 * MAXM + j];
        const float w2 = wlds[2 * MAXM + j];
        const float w3 = wlds[3 * MAXM + j];
        const float* rp = img + (size_t)row * ROW_F + start_f;
        if (a0ok) {
            const float4 v = *(const float4*)(rp + f0);
            accA[0].x = fmaf(w0, v.x, accA[0].x); accA[0].y = fmaf(w0, v.y, accA[0].y);
            accA[0].z = fmaf(w0, v.z, accA[0].z); accA[0].w = fmaf(w0, v.w, accA[0].w);
            accA[1].x = fmaf(w1, v.x, accA[1].x); accA[1].y = fmaf(w1, v.y, accA[1].y);
            accA[1].z = fmaf(w1, v.z, accA[1].z); accA[1].w = fmaf(w1, v.w, accA[1].w);
            accA[2].x = fmaf(w2, v.x, accA[2].x); accA[2].y = fmaf(w2, v.y, accA[2].y);
            accA[2].z = fmaf(w2, v.z, accA[2].z); accA[2].w = fmaf(w2, v.w, accA[2].w);
            accA[3].x = fmaf(w3, v.x, accA[3].x); accA[3].y = fmaf(w3, v.y, accA[3].y);
            accA[3].z = fmaf(w3, v.z, accA[3].z); accA[3].w = fmaf(w3, v.w, accA[3].w);
        }
        if (a1ok) {
            const float4 v = *(const float4*)(rp + f1);
            accB[0].x = fmaf(w0, v.x, accB[0].x); accB[0].y = fmaf(w0, v.y, accB[0].y);
            accB[0].z = fmaf(w0, v.z, accB[0].z); accB[0].w = fmaf(w0, v.w, accB[0].w);
            accB[1].x = fmaf(w1, v.x, accB[1].x); accB[1].y = fmaf(w1, v.y, accB[1].y);
            accB[1].z = fmaf(w1, v.z, accB[1].z); accB[1].w = fmaf(w1, v.w, accB[1].w);
            accB[2].x = fmaf(w2, v.x, accB[2].x); accB[2].y = fmaf(w2, v.y, accB[2].y);
            accB[2].z = fmaf(w2, v.z, accB[2].z); accB[2].w = fmaf(w2, v.w, accB[2].w);
            accB[3].x = fmaf(w3, v.x, accB[3].x); accB[3].y = fmaf(w3, v.y, accB[3].y);
            accB[3].z = fmaf(w3, v.z, accB[3].z); accB[3].w = fmaf(w3, v.w, accB[3].w);
        }
    }
    if (a0ok) {
        #pragma unroll
        for (int g = 0; g < G; ++g) *(float4*)(ldsrow + g * LROW + f0) = accA[g];
    }
    if (a1ok) {
        #pragma unroll
        for (int g = 0; g < G; ++g) *(float4*)(ldsrow + g * LROW + f1) = accB[g];
    }
    __syncthreads();

    // ---- compute: wave gsel emits output row p0+gsel at column q ----
    if (qact) {
        const float* l = ldsrow + gsel * LROW;
        const int i0 = li0 - start_f, i1 = li1 - start_f, i2 = li2 - start_f;
        const int i3 = li3 - start_f, i4 = li4 - start_f, i5 = li5 - start_f;
        float a0, a1, a2;
        a0 = hw0 * l[i0 + 0]; a1 = hw0 * l[i0 + 1]; a2 = hw0 * l[i0 + 2];
        a0 = fmaf(hw1, l[i1 + 0], a0); a1 = fmaf(hw1, l[i1 + 1], a1); a2 = fmaf(hw1, l[i1 + 2], a2);
        a0 = fmaf(hw2, l[i2 + 0], a0); a1 = fmaf(hw2, l[i2 + 1], a1); a2 = fmaf(hw2, l[i2 + 2], a2);
        a0 = fmaf(hw3, l[i3 + 0], a0); a1 = fmaf(hw3, l[i3 + 1], a1); a2 = fmaf(hw3, l[i3 + 2], a2);
        a0 = fmaf(hw4, l[i4 + 0], a0); a1 = fmaf(hw4, l[i4 + 1], a1); a2 = fmaf(hw4, l[i4 + 2], a2);
        a0 = fmaf(hw5, l[i5 + 0], a0); a1 = fmaf(hw5, l[i5 + 1], a1); a2 = fmaf(hw5, l[i5 + 2], a2);
        const size_t o = (((size_t)box * OUT + (p0 + gsel)) * OUT + q) * 3;
        out[o + 0] = a0;
        out[o + 1] = a1;
        out[o + 2] = a2;
    }
}

// ---------------- Fallback (round-4 single kernel, no workspace) ----------------
__global__ __launch_bounds__(256) void crop_resize_fallback(
    const float* __restrict__ scores, const float* __restrict__ boxes,
    const float* __restrict__ img, float* __restrict__ out)
{
    const int p = blockIdx.x, box = blockIdx.y;
    const float b0 = boxes[box*4+0], b1 = boxes[box*4+1];
    const float b2 = boxes[box*4+2], b3 = boxes[box*4+3];
    const int y0 = (int)(b0*(float)IMG_H), x0 = (int)(b1*(float)IMG_W);
    const int y1 = (int)(b2*(float)IMG_H), x1 = (int)(b3*(float)IMG_W);
    const int ch = max(y1-y0,1), cw = max(x1-x0,1);
    const bool valid = (scores[0]>=TH)&&(scores[box]>=TH)&&(b1>=0.0f)&&(b3<=1.0f);
    const float vmask = valid?1.0f:0.0f;
    float wh[TAPS]; int ih[TAPS];
    {
        const float src = ((float)p+0.5f)*((float)ch/(float)OUT)-0.5f;
        const int base = (int)floorf(src)-2;
        float s = 0.0f;
        #pragma unroll
        for (int a = 0; a < TAPS; ++a) {
            const float d = src-(float)(base+a);
            const float w = (fabsf(d)<3.0f)?sincf(d)*sincf(d*(1.0f/3.0f)):0.0f;
            wh[a]=w; s+=w;
            int t=base+a; t=t<0?0:t; t=t>ch-1?ch-1:t; ih[a]=t+y0;
        }
        const float inv = 1.0f/s;
        #pragma unroll
        for (int a = 0; a < TAPS; ++a) wh[a]*=inv;
    }
    const int start_f = (x0*3)&~3;
    const int end_f = (x0+cw)*3;
    const int n_f = end_f-start_f;
    __shared__ float lds[6152];
    {
        const float* r0 = img+(size_t)ih[0]*ROW_F+start_f;
        const float* r1 = img+(size_t)ih[1]*ROW_F+start_f;
        const float* r2 = img+(size_t)ih[2]*ROW_F+start_f;
        const float* r3 = img+(size_t)ih[3]*ROW_F+start_f;
        const float* r4 = img+(size_t)ih[4]*ROW_F+start_f;
        const float* r5 = img+(size_t)ih[5]*ROW_F+start_f;
        for (int f = threadIdx.x*4; f < n_f; f += 256*4) {
            const float4 u0=*(const float4*)(r0+f), u1=*(const float4*)(r1+f);
            const float4 u2=*(const float4*)(r2+f), u3=*(const float4*)(r3+f);
            const float4 u4=*(const float4*)(r4+f), u5=*(const float4*)(r5+f);
            float4 acc;
            acc.x=wh[0]*u0.x+wh[1]*u1.x+wh[2]*u2.x+wh[3]*u3.x+wh[4]*u4.x+wh[5]*u5.x;
            acc.y=wh[0]*u0.y+wh[1]*u1.y+wh[2]*u2.y+wh[3]*u3.y+wh[4]*u4.y+wh[5]*u5.y;
            acc.z=wh[0]*u0.z+wh[1]*u1.z+wh[2]*u2.z+wh[3]*u3.z+wh[4]*u4.z+wh[5]*u5.z;
            acc.w=wh[0]*u0.w+wh[1]*u1.w+wh[2]*u2.w+wh[3]*u3.w+wh[4]*u4.w+wh[5]*u5.w;
            *(float4*)(lds+f)=acc;
        }
    }
    __syncthreads();
    const float wscale = (float)cw/(float)OUT;
    for (int q = threadIdx.x; q < OUT; q += 256) {
        const float src = ((float)q+0.5f)*wscale-0.5f;
        const int basew = (int)floorf(src)-2;
        float ww[TAPS]; float s = 0.0f;
        #pragma unroll
        for (int k = 0; k < TAPS; ++k) {
            const float d = src-(float)(basew+k);
            const float w = (fabsf(d)<3.0f)?sincf(d)*sincf(d*(1.0f/3.0f)):0.0f;
            ww[k]=w; s+=w;
        }
        const float inv = 1.0f/s;
        float a0=0,a1=0,a2=0;
        #pragma unroll
        for (int k = 0; k < TAPS; ++k) {
            int t=basew+k; t=t<0?0:t; t=t>cw-1?cw-1:t;
            const int hb=(x0+t)*3-start_f;
            a0=fmaf(ww[k],lds[hb+0],a0);
            a1=fmaf(ww[k],lds[hb+1],a1);
            a2=fmaf(ww[k],lds[hb+2],a2);
        }
        const float mfac = vmask*inv;
        const size_t o = (((size_t)box*OUT+p)*OUT+q)*3;
        out[o+0]=a0*mfac; out[o+1]=a1*mfac; out[o+2]=a2*mfac;
    }
}

extern "C" void kernel_launch(void* const* d_in, const int* in_sizes, int n_in,
                              void* d_out, int out_size, void* d_ws, size_t ws_size,
                              hipStream_t stream) {
    const float* scores = (const float*)d_in[0];   // (100,)
    const float* boxes  = (const float*)d_in[1];   // (100,4)
    const float* img    = (const float*)d_in[2];   // (1,2048,2048,3)
    float* out = (float*)d_out;                    // (10,260,260,3)

    const size_t tab_bytes = (size_t)NB * OUT * 16 * sizeof(float);  // 166,400 B each
    if (ws_size < 2 * tab_bytes) {
        crop_resize_fallback<<<dim3(OUT, NB), dim3(256), 0, stream>>>(scores, boxes, img, out);
        return;
    }
    float* htab = (float*)d_ws;
    float* vtab = (float*)((char*)d_ws + tab_bytes);

    tables_kernel<<<dim3(NB), dim3(320), 0, stream>>>(scores, boxes, htab, vtab);
    crop_resize_pg<<<dim3(SEGS, OUT / G, NB), dim3(256), 0, stream>>>(img, boxes, htab, vtab, out);
}